// Round 15
// baseline (185.594 us; speedup 1.0000x reference)
//
#include <hip/hip_runtime.h>
#include <stdint.h>

typedef __attribute__((ext_vector_type(8))) short short8;
typedef __attribute__((ext_vector_type(4))) float floatx4;
typedef __attribute__((ext_vector_type(16))) float f32x16;
typedef __attribute__((ext_vector_type(4))) unsigned int uint4v;

#define D_MODEL 1024
#define SEQ     2048
#define NHEAD   16
#define HDIM    64
#define BATCH   4
#define NW      (D_MODEL * D_MODEL)

__device__ __forceinline__ unsigned short f2b(float f) {
  unsigned int u = __builtin_bit_cast(unsigned int, f);
  u += 0x7FFFu + ((u >> 16) & 1u);
  return (unsigned short)(u >> 16);
}

__device__ __forceinline__ floatx4 mfma16(short8 a, short8 b, floatx4 c) {
  return __builtin_amdgcn_mfma_f32_16x16x32_bf16(a, b, c, 0, 0, 0);
}
__device__ __forceinline__ f32x16 mfma32(short8 a, short8 b, f32x16 c) {
  return __builtin_amdgcn_mfma_f32_32x32x16_bf16(a, b, c, 0, 0, 0);
}
__device__ __forceinline__ unsigned int cvtpk(float lo, float hi) {
  unsigned int r;
  asm("v_cvt_pk_bf16_f32 %0, %1, %2" : "=v"(r) : "v"(lo), "v"(hi));
  return r;
}
__device__ __forceinline__ void pl32swap(unsigned int &a, unsigned int &b) {
  asm("v_permlane32_swap_b32 %0, %1" : "+v"(a), "+v"(b));
}
__device__ __forceinline__ float expfast(float x) {
  return __builtin_amdgcn_exp2f(x);
}

#define GLL16(gsrc, ldst)                                                     \
  __builtin_amdgcn_global_load_lds(                                           \
      (const __attribute__((address_space(1))) void*)(gsrc),                  \
      (__attribute__((address_space(3))) void*)(ldst), 16, 0, 0)

// counted-vmcnt barrier (v10-validated sync pattern; rule 18 sched_barrier pin)
#define CBAR(N)                                                               \
  do {                                                                        \
    asm volatile("s_waitcnt vmcnt(" #N ")" ::: "memory");                     \
    __builtin_amdgcn_s_barrier();                                             \
    __builtin_amdgcn_sched_barrier(0);                                        \
  } while (0)

// ---------------- fused prep: weights cvt + mask prep + x cvt ----------------
__global__ void prep(const float* __restrict__ x, unsigned short* __restrict__ xb,
                     const float* __restrict__ Wq, const float* __restrict__ Wk,
                     const float* __restrict__ Wv, const float* __restrict__ Wo,
                     unsigned short* __restrict__ Wqkv,
                     unsigned short* __restrict__ Wob,
                     const int* __restrict__ mask, float* __restrict__ maskb,
                     unsigned int* __restrict__ flags2,
                     const float* __restrict__ bq, const float* __restrict__ bk,
                     const float* __restrict__ bv, float* __restrict__ bqkv) {
  const int which = blockIdx.y;
  const int tid = threadIdx.x;
  int idx = (blockIdx.x * 256 + tid) * 4;
  int stride = gridDim.x * 256 * 4;
  if (which == 4) {
    for (int i = idx; i < BATCH * SEQ; i += stride) {
      int4 mv = *reinterpret_cast<const int4*>(mask + i);
      float4 o;
      o.x = mv.x ? 0.f : -1e10f;
      o.y = mv.y ? 0.f : -1e10f;
      o.z = mv.z ? 0.f : -1e10f;
      o.w = mv.w ? 0.f : -1e10f;
      *reinterpret_cast<float4*>(maskb + i) = o;
    }
    if (blockIdx.x < 4) {
      const int b = blockIdx.x;
      if (tid < 64) {
        int ok = 0;
        if (tid < 32) {
          ok = 1;
          for (int i = 0; i < 64; ++i) ok &= mask[b * SEQ + tid * 64 + i];
        }
        unsigned long long bal = __ballot(ok);
        if (tid == 0) flags2[b] = (unsigned int)bal;
      }
      const int i = b * 256 + tid;  // 0..1023
      bqkv[i] = bq[i];
      bqkv[1024 + i] = bk[i];
      bqkv[2048 + i] = bv[i];
    }
    return;
  }
  if (which == 5) {
    const int NX = BATCH * SEQ * D_MODEL;
    for (int i = idx; i < NX; i += stride) {
      float4 v = *reinterpret_cast<const float4*>(x + i);
      ushort4 o;
      o.x = f2b(v.x); o.y = f2b(v.y); o.z = f2b(v.z); o.w = f2b(v.w);
      *reinterpret_cast<ushort4*>(xb + i) = o;
    }
    return;
  }
  const float* s = which == 0 ? Wq : which == 1 ? Wk : which == 2 ? Wv : Wo;
  unsigned short* d = which < 3 ? Wqkv + (size_t)which * NW : Wob;
  for (int i = idx; i < NW; i += stride) {
    float4 v = *reinterpret_cast<const float4*>(s + i);
    ushort4 o;
    o.x = f2b(v.x); o.y = f2b(v.y); o.z = f2b(v.z); o.w = f2b(v.w);
    *reinterpret_cast<ushort4*>(d + i) = o;
  }
}

// ---------------- GEMM v4: 256x128 tile, 3-buffer counted-vmcnt ring ----------
// 512 threads, 8 waves (4M x 2N), each 64x64 output (same frag math as v2).
// 3 LDS K-tile buffers (144KB, R13-proven static size) -> prefetch distance 2,
// ONE vmcnt(6)+s_barrier per K-tile, never draining until tail (T4/m218).
// T2 swizzle + T1 XCD swizzle kept. K=1024 (NT=16) hardcoded.
// MODE 1: QKV fused (Q pre-scale, V transposed to VT). MODE 2: f32 C.
template <int MODE>
__global__ __launch_bounds__(512) void gemm_r3(
    const unsigned short* __restrict__ A, const unsigned short* __restrict__ B,
    const float* __restrict__ bias, void* __restrict__ C,
    unsigned short* __restrict__ VT, int M, int N, int K) {
  __shared__ __align__(16) unsigned short As[3][256 * 64];  // 3 x 32KB
  __shared__ __align__(16) unsigned short Bs[3][128 * 64];  // 3 x 16KB
  const int tid = threadIdx.x;
  const int w = tid >> 6, l = tid & 63, lg = l >> 4, li = l & 15;
  const int GX = (MODE == 1) ? 24 : 8;   // N/128
  const int NWG = GX * (M >> 8);         // x (M/256)
  int id = blockIdx.y * GX + blockIdx.x;
  id = (id & 7) * (NWG >> 3) + (id >> 3);
  const int m0 = (id / GX) * 256, n0 = (id % GX) * 128;
  const int wr = w >> 1, wc = w & 1;  // wave output at (wr*64, wc*64)

  floatx4 acc[4][4];
#pragma unroll
  for (int m = 0; m < 4; ++m)
#pragma unroll
    for (int n = 0; n < 4; ++n) acc[m][n] = (floatx4){0.f, 0.f, 0.f, 0.f};

  // Stage K-tile T into buffer BUF: A 4 rounds + B 2 rounds = 6 GLL/thread.
  // chunk c = p*512+tid -> row=c>>3, slot=c&7; source col pre-swizzled
  // (slot^(row&7)) so linear LDS dst + XOR'd read = conflict-free (rule 21).
#define GSTAGE(BUF, T)                                                         \
  do {                                                                         \
    _Pragma("unroll") for (int p = 0; p < 4; ++p) {                            \
      const int c = p * 512 + tid;                                             \
      const int row = c >> 3;                                                  \
      const int co = ((c & 7) ^ (row & 7)) * 8;                                \
      GLL16(A + (size_t)(m0 + row) * K + (T) * 64 + co,                        \
            &As[BUF][(p * 512 + w * 64) * 8]);                                 \
    }                                                                          \
    _Pragma("unroll") for (int p = 0; p < 2; ++p) {                            \
      const int c = p * 512 + tid;                                             \
      const int row = c >> 3;                                                  \
      const int co = ((c & 7) ^ (row & 7)) * 8;                                \
      GLL16(B + (size_t)(n0 + row) * K + (T) * 64 + co,                        \
            &Bs[BUF][(p * 512 + w * 64) * 8]);                                 \
    }                                                                          \
  } while (0)

#define GCOMP(BUF)                                                             \
  do {                                                                         \
    _Pragma("unroll") for (int kk = 0; kk < 2; ++kk) {                         \
      short8 af[4], bfr[4];                                                    \
      _Pragma("unroll") for (int m = 0; m < 4; ++m)                            \
        af[m] = *reinterpret_cast<const short8*>(                              \
            &As[BUF][(wr * 64 + m * 16 + li) * 64 +                            \
                     (((kk * 4 + lg) ^ (li & 7)) * 8)]);                       \
      _Pragma("unroll") for (int n = 0; n < 4; ++n)                            \
        bfr[n] = *reinterpret_cast<const short8*>(                             \
            &Bs[BUF][(wc * 64 + n * 16 + li) * 64 +                            \
                     (((kk * 4 + lg) ^ (li & 7)) * 8)]);                       \
      __builtin_amdgcn_s_setprio(1);                                           \
      _Pragma("unroll") for (int m = 0; m < 4; ++m)                            \
        _Pragma("unroll") for (int n = 0; n < 4; ++n)                          \
            acc[m][n] = mfma16(af[m], bfr[n], acc[m][n]);                      \
      __builtin_amdgcn_s_setprio(0);                                           \
    }                                                                          \
  } while (0)

  // NT=16 K-tiles, buffer = t%3. Ring: STAGE(t+2) -> COMP(t) -> vmcnt(6)+bar
  // (outstanding = t+1(6)+t+2(6)=12 -> retires exactly t+1; no full drain).
  GSTAGE(0, 0);
  GSTAGE(1, 1);
  CBAR(6);  // tile 0 ready; tile 1 in flight
#pragma unroll 1
  for (int tb = 0; tb < 12; tb += 3) {
    GSTAGE(2, tb + 2); GCOMP(0); CBAR(6);
    GSTAGE(0, tb + 3); GCOMP(1); CBAR(6);
    GSTAGE(1, tb + 4); GCOMP(2); CBAR(6);
  }
  GSTAGE(2, 14); GCOMP(0); CBAR(6);   // t=12
  GSTAGE(0, 15); GCOMP(1); CBAR(6);   // t=13 (retires tile 14)
  GCOMP(2); CBAR(0);                  // t=14 (drain: tile 15 ready)
  GCOMP(0);                           // t=15
#undef GSTAGE
#undef GCOMP

#pragma unroll
  for (int m = 0; m < 4; ++m)
#pragma unroll
    for (int n = 0; n < 4; ++n) {
      const int gcol = n0 + wc * 64 + n * 16 + li;
      const float bv = bias[gcol];
      const int grow0 = m0 + wr * 64 + m * 16 + lg * 4;
      if (MODE == 1 && n0 >= 2048) {
        const int vc = gcol - 2048;
        const int hh = vc >> 6, dd = vc & 63;
        const int b = grow0 >> 11, s0 = grow0 & 2047;
        ushort4 pk;
        pk.x = f2b(acc[m][n][0] + bv);
        pk.y = f2b(acc[m][n][1] + bv);
        pk.z = f2b(acc[m][n][2] + bv);
        pk.w = f2b(acc[m][n][3] + bv);
        *reinterpret_cast<ushort4*>(
            &VT[((size_t)((b * NHEAD + hh) * HDIM + dd)) * SEQ + s0]) = pk;
      } else {
        const float scl =
            (MODE == 1 && gcol < 1024) ? 0.18033688011112042f : 1.f;
#pragma unroll
        for (int r = 0; r < 4; ++r) {
          const float val = (acc[m][n][r] + bv) * scl;
          if (MODE == 2)
            reinterpret_cast<float*>(C)[(size_t)(grow0 + r) * N + gcol] = val;
          else
            reinterpret_cast<unsigned short*>(C)[(size_t)(grow0 + r) * N + gcol] =
                f2b(val);
        }
      }
    }
}

// ---------------- Flash attention v7 (best: 95.6 us; frozen) ----------------
__global__ __launch_bounds__(512) void attn_v7(
    const unsigned short* __restrict__ QKV, const unsigned short* __restrict__ VT,
    const float* __restrict__ maskb, const unsigned int* __restrict__ flags2,
    unsigned short* __restrict__ O) {
  __shared__ __align__(16) unsigned short Kl[2][64 * 64];
  __shared__ __align__(16) unsigned short Vl[2][64 * 64];
  const int tid = threadIdx.x, w = tid >> 6, l = tid & 63;
  const int qi = l & 31, hi = l >> 5;
  const int bid = blockIdx.x;
  const int qblk = bid >> 6, bh = bid & 63, b = bh >> 4, h = bh & 15;
  const int q0 = qblk * 256 + w * 32;

  const unsigned short* qptr = QKV + (size_t)(b * SEQ + q0 + qi) * 3072 + h * 64;
  short8 qf[4];
#pragma unroll
  for (int ds = 0; ds < 4; ++ds)
    qf[ds] = *reinterpret_cast<const short8*>(qptr + ds * 16 + hi * 8);

  int off[2][4];
#pragma unroll
  for (int kb = 0; kb < 2; ++kb)
#pragma unroll
    for (int ds = 0; ds < 4; ++ds)
      off[kb][ds] = (kb * 32 + qi) * 64 + (((ds * 2 + hi) ^ (qi & 7)) * 8);

  const int srow = tid >> 3;
  const int swz = ((tid & 7) ^ (srow & 7)) * 8;
  const int ldst = w * 512;  // wave-uniform LDS base (ushort units)
  const unsigned short* kp0 =
      QKV + (size_t)(b * SEQ) * 3072 + D_MODEL + h * 64 + (size_t)srow * 3072 + swz;
  const unsigned short* vp0 =
      VT + (size_t)((b * NHEAD + h) * HDIM) * SEQ + (size_t)srow * SEQ + swz;

#define STAGE(BUF)                                                             \
  do {                                                                         \
    GLL16(kp0, &Kl[BUF][ldst]);                                                \
    GLL16(vp0, &Vl[BUF][ldst]);                                                \
    kp0 += 64 * 3072; vp0 += 64;                                               \
  } while (0)

  const float* mrow = maskb + b * SEQ;
  const unsigned int fl = flags2[b];
  f32x16 oa[2] = {};
  float l_run = 0.f;  // per-lane partial (own k-half); combined in epilogue

#define TILE(BUF, KT)                                                          \
  do {                                                                         \
    f32x16 pa0 = {}, pa1 = {};                                                 \
    __builtin_amdgcn_s_setprio(1);                                             \
    _Pragma("unroll") for (int ds = 0; ds < 4; ++ds) {                         \
      const short8 kf0 =                                                       \
          *reinterpret_cast<const short8*>(&Kl[BUF][off[0][ds]]);              \
      const short8 kf1 =                                                       \
          *reinterpret_cast<const short8*>(&Kl[BUF][off[1][ds]]);              \
      pa0 = mfma32(kf0, qf[ds], pa0);                                          \
      pa1 = mfma32(kf1, qf[ds], pa1);                                          \
    }                                                                          \
    __builtin_amdgcn_s_setprio(0);                                             \
    if (!((fl >> (KT)) & 1)) { /* slow path: some keys masked */               \
      _Pragma("unroll") for (int rq = 0; rq < 4; ++rq) {                       \
        const float4 m0 = *reinterpret_cast<const float4*>(                    \
            mrow + (KT) * 64 + rq * 8 + hi * 4);                               \
        const float4 m1 = *reinterpret_cast<const float4*>(                    \
            mrow + (KT) * 64 + 32 + rq * 8 + hi * 4);                          \
        pa0[rq * 4 + 0] += m0.x; pa0[rq * 4 + 1] += m0.y;                      \
        pa0[rq * 4 + 2] += m0.z; pa0[rq * 4 + 3] += m0.w;                      \
        pa1[rq * 4 + 0] += m1.x; pa1[rq * 4 + 1] += m1.y;                      \
        pa1[rq * 4 + 2] += m1.z; pa1[rq * 4 + 3] += m1.w;                      \
      }                                                                        \
    }                                                                          \
    float r0 = 0.f, r1 = 0.f, r2 = 0.f, r3 = 0.f;                              \
    _Pragma("unroll") for (int r = 0; r < 16; r += 4) {                        \
      float p;                                                                 \
      p = expfast(pa0[r + 0]); pa0[r + 0] = p; r0 += p;                        \
      p = expfast(pa0[r + 1]); pa0[r + 1] = p; r1 += p;                        \
      p = expfast(pa0[r + 2]); pa0[r + 2] = p; r2 += p;                        \
      p = expfast(pa0[r + 3]); pa0[r + 3] = p; r3 += p;                        \
      p = expfast(pa1[r + 0]); pa1[r + 0] = p; r0 += p;                        \
      p = expfast(pa1[r + 1]); pa1[r + 1] = p; r1 += p;                        \
      p = expfast(pa1[r + 2]); pa1[r + 2] = p; r2 += p;                        \
      p = expfast(pa1[r + 3]); pa1[r + 3] = p; r3 += p;                        \
    }                                                                          \
    l_run += (r0 + r1) + (r2 + r3);                                            \
    unsigned int c0[8], c1[8];                                                 \
    _Pragma("unroll") for (int u2 = 0; u2 < 8; ++u2) {                         \
      c0[u2] = cvtpk(pa0[2 * u2], pa0[2 * u2 + 1]);                            \
      c1[u2] = cvtpk(pa1[2 * u2], pa1[2 * u2 + 1]);                            \
    }                                                                          \
    pl32swap(c0[0], c0[2]); pl32swap(c0[1], c0[3]);                            \
    pl32swap(c0[4], c0[6]); pl32swap(c0[5], c0[7]);                            \
    pl32swap(c1[0], c1[2]); pl32swap(c1[1], c1[3]);                            \
    pl32swap(c1[4], c1[6]); pl32swap(c1[5], c1[7]);                            \
    __builtin_amdgcn_s_setprio(1);                                             \
    _Pragma("unroll") for (int ks = 0; ks < 4; ++ks) {                         \
      const int kb = ks >> 1, hf = (ks & 1) * 4;                               \
      const short8 pf = __builtin_bit_cast(                                    \
          short8, kb ? (uint4v){c1[hf], c1[hf + 1], c1[hf + 2], c1[hf + 3]}    \
                     : (uint4v){c0[hf], c0[hf + 1], c0[hf + 2], c0[hf + 3]});  \
      const short8 vf0 =                                                       \
          *reinterpret_cast<const short8*>(&Vl[BUF][off[0][ks]]);              \
      const short8 vf1 =                                                       \
          *reinterpret_cast<const short8*>(&Vl[BUF][off[1][ks]]);              \
      oa[0] = mfma32(vf0, pf, oa[0]);                                          \
      oa[1] = mfma32(vf1, pf, oa[1]);                                          \
    }                                                                          \
    __builtin_amdgcn_s_setprio(0);                                             \
  } while (0)

  STAGE(0);  // tile 0
  __syncthreads();
#pragma unroll 1
  for (int kt = 0; kt < 32; kt += 2) {
    STAGE(1);  // tile kt+1 in flight while computing kt
    TILE(0, kt);
    __syncthreads();
    if (kt + 2 < 32) STAGE(0);  // tile kt+2
    TILE(1, kt + 1);
    __syncthreads();
  }
#undef STAGE
#undef TILE

  // epilogue: combine lane-partial l across k-halves, normalize, repack, store
  l_run += __shfl_xor(l_run, 32);
  const float rinv = 1.f / l_run;
  unsigned int u[2][8];
#pragma unroll
  for (int vb = 0; vb < 2; ++vb) {
#pragma unroll
    for (int uu = 0; uu < 8; ++uu)
      u[vb][uu] = cvtpk(oa[vb][2 * uu] * rinv, oa[vb][2 * uu + 1] * rinv);
    pl32swap(u[vb][0], u[vb][2]);
    pl32swap(u[vb][1], u[vb][3]);
    pl32swap(u[vb][4], u[vb][6]);
    pl32swap(u[vb][5], u[vb][7]);
  }
  unsigned short* optr = O + (size_t)(b * SEQ + q0 + qi) * D_MODEL + h * 64;
#pragma unroll
  for (int cix = 0; cix < 4; ++cix) {
    const int vb = cix >> 1, hf = (cix & 1) * 4;
    *reinterpret_cast<short8*>(optr + cix * 16 + hi * 8) = __builtin_bit_cast(
        short8,
        (uint4v){u[vb][hf], u[vb][hf + 1], u[vb][hf + 2], u[vb][hf + 3]});
  }
}

// ---------------- launch ----------------
extern "C" void kernel_launch(void* const* d_in, const int* in_sizes, int n_in,
                              void* d_out, int out_size, void* d_ws, size_t ws_size,
                              hipStream_t stream) {
  const float* x  = (const float*)d_in[0];
  const int* mask = (const int*)d_in[1];
  const float* Wq = (const float*)d_in[2];
  const float* bq = (const float*)d_in[3];
  const float* Wk = (const float*)d_in[4];
  const float* bk = (const float*)d_in[5];
  const float* Wv = (const float*)d_in[6];
  const float* bv = (const float*)d_in[7];
  const float* Wo = (const float*)d_in[8];
  const float* bo = (const float*)d_in[9];

  char* ws = (char*)d_ws;
  const size_t SZ_X = (size_t)BATCH * SEQ * D_MODEL * 2;  // 16 MB
  unsigned short* xb    = (unsigned short*)(ws);                    // 16 MB @ 0
  unsigned short* Wqkvb = (unsigned short*)(ws + SZ_X);             // 6 MB @ 16M
  unsigned short* Wob   = (unsigned short*)(ws + SZ_X + 6u * 1024 * 1024);  // @ 22M
  unsigned short* QKVb  = (unsigned short*)(ws + 24u * 1024 * 1024);        // 48 MB
  unsigned short* VTb   = (unsigned short*)(ws + 72u * 1024 * 1024);        // 16 MB
  float*          bqkv  = (float*)(ws + 88u * 1024 * 1024);                 // 12 KB
  float*          maskb = (float*)(ws + 88u * 1024 * 1024 + 16384);         // 32 KB
  unsigned int*   flag2 = (unsigned int*)(ws + 88u * 1024 * 1024 + 49152);  // 16 B
  unsigned short* Ob    = xb;  // reuse: xb dead after QKV GEMM

  const int M = BATCH * SEQ;             // 8192

  prep<<<dim3(512, 6), 256, 0, stream>>>(x, xb, Wq, Wk, Wv, Wo, Wqkvb, Wob,
                                         mask, maskb, flag2, bq, bk, bv, bqkv);

  gemm_r3<1><<<dim3(3 * D_MODEL / 128, M / 256), 512, 0, stream>>>(
      xb, Wqkvb, bqkv, QKVb, VTb, M, 3 * D_MODEL, D_MODEL);

  attn_v7<<<BATCH * NHEAD * (SEQ / 256), 512, 0, stream>>>(QKVb, VTb, maskb,
                                                           flag2, Ob);

  gemm_r3<2><<<dim3(D_MODEL / 128, M / 256), 512, 0, stream>>>(
      Ob, Wob, bo, d_out, nullptr, M, D_MODEL, D_MODEL);
}

// Round 16
// 182.737 us; speedup vs baseline: 1.0156x; 1.0156x over previous
//
#include <hip/hip_runtime.h>
#include <stdint.h>

typedef __attribute__((ext_vector_type(8))) short short8;
typedef __attribute__((ext_vector_type(4))) float floatx4;
typedef __attribute__((ext_vector_type(16))) float f32x16;
typedef __attribute__((ext_vector_type(4))) unsigned int uint4v;

#define D_MODEL 1024
#define SEQ     2048
#define NHEAD   16
#define HDIM    64
#define BATCH   4
#define NW      (D_MODEL * D_MODEL)

__device__ __forceinline__ unsigned short f2b(float f) {
  unsigned int u = __builtin_bit_cast(unsigned int, f);
  u += 0x7FFFu + ((u >> 16) & 1u);
  return (unsigned short)(u >> 16);
}

__device__ __forceinline__ floatx4 mfma16(short8 a, short8 b, floatx4 c) {
  return __builtin_amdgcn_mfma_f32_16x16x32_bf16(a, b, c, 0, 0, 0);
}
__device__ __forceinline__ f32x16 mfma32(short8 a, short8 b, f32x16 c) {
  return __builtin_amdgcn_mfma_f32_32x32x16_bf16(a, b, c, 0, 0, 0);
}
__device__ __forceinline__ unsigned int cvtpk(float lo, float hi) {
  unsigned int r;
  asm("v_cvt_pk_bf16_f32 %0, %1, %2" : "=v"(r) : "v"(lo), "v"(hi));
  return r;
}
__device__ __forceinline__ void pl32swap(unsigned int &a, unsigned int &b) {
  asm("v_permlane32_swap_b32 %0, %1" : "+v"(a), "+v"(b));
}
__device__ __forceinline__ float expfast(float x) {
  return __builtin_amdgcn_exp2f(x);
}

#define GLL16(gsrc, ldst)                                                     \
  __builtin_amdgcn_global_load_lds(                                           \
      (const __attribute__((address_space(1))) void*)(gsrc),                  \
      (__attribute__((address_space(3))) void*)(ldst), 16, 0, 0)

// ---------------- fused prep: weights cvt + mask prep + x cvt ----------------
// blockIdx.y: 0..3 -> Wq,Wk,Wv (into Wqkv) / Wo cvt; 4 -> mask bias + per-64-
// chunk valid flags + bias concat; 5 -> x cvt.
__global__ void prep(const float* __restrict__ x, unsigned short* __restrict__ xb,
                     const float* __restrict__ Wq, const float* __restrict__ Wk,
                     const float* __restrict__ Wv, const float* __restrict__ Wo,
                     unsigned short* __restrict__ Wqkv,
                     unsigned short* __restrict__ Wob,
                     const int* __restrict__ mask, float* __restrict__ maskb,
                     unsigned int* __restrict__ flags2,
                     const float* __restrict__ bq, const float* __restrict__ bk,
                     const float* __restrict__ bv, float* __restrict__ bqkv) {
  const int which = blockIdx.y;
  const int tid = threadIdx.x;
  int idx = (blockIdx.x * 256 + tid) * 4;
  int stride = gridDim.x * 256 * 4;
  if (which == 4) {
    for (int i = idx; i < BATCH * SEQ; i += stride) {
      int4 mv = *reinterpret_cast<const int4*>(mask + i);
      float4 o;
      o.x = mv.x ? 0.f : -1e10f;
      o.y = mv.y ? 0.f : -1e10f;
      o.z = mv.z ? 0.f : -1e10f;
      o.w = mv.w ? 0.f : -1e10f;
      *reinterpret_cast<float4*>(maskb + i) = o;
    }
    if (blockIdx.x < 4) {
      const int b = blockIdx.x;
      if (tid < 64) {
        int ok = 0;
        if (tid < 32) {
          ok = 1;
          for (int i = 0; i < 64; ++i) ok &= mask[b * SEQ + tid * 64 + i];
        }
        unsigned long long bal = __ballot(ok);
        if (tid == 0) flags2[b] = (unsigned int)bal;
      }
      const int i = b * 256 + tid;  // 0..1023
      bqkv[i] = bq[i];
      bqkv[1024 + i] = bk[i];
      bqkv[2048 + i] = bv[i];
    }
    return;
  }
  if (which == 5) {
    const int NX = BATCH * SEQ * D_MODEL;
    for (int i = idx; i < NX; i += stride) {
      float4 v = *reinterpret_cast<const float4*>(x + i);
      ushort4 o;
      o.x = f2b(v.x); o.y = f2b(v.y); o.z = f2b(v.z); o.w = f2b(v.w);
      *reinterpret_cast<ushort4*>(xb + i) = o;
    }
    return;
  }
  const float* s = which == 0 ? Wq : which == 1 ? Wk : which == 2 ? Wv : Wo;
  unsigned short* d = which < 3 ? Wqkv + (size_t)which * NW : Wob;
  for (int i = idx; i < NW; i += stride) {
    float4 v = *reinterpret_cast<const float4*>(s + i);
    ushort4 o;
    o.x = f2b(v.x); o.y = f2b(v.y); o.z = f2b(v.z); o.w = f2b(v.w);
    *reinterpret_cast<ushort4*>(d + i) = o;
  }
}

// ---------------- GEMM v2: double-buffered 2-phase + T2 swizzle ----------------
// (R9/R14 state — best measured; at/above the documented 2-phase ceiling.)
template <int MODE>
__global__ __launch_bounds__(256) void gemm_bt(
    const unsigned short* __restrict__ A, const unsigned short* __restrict__ B,
    const float* __restrict__ bias, void* __restrict__ C,
    unsigned short* __restrict__ VT, int M, int N, int K) {
  __shared__ __align__(16) unsigned short As[2][128 * 64];
  __shared__ __align__(16) unsigned short Bs[2][128 * 64];
  const int tid = threadIdx.x;
  const int w = tid >> 6, l = tid & 63, lg = l >> 4, li = l & 15;
  const int GX = (MODE == 1) ? 24 : 8;      // N/128
  const int NWG = GX * 64;                   // M/128 = 64
  int id = blockIdx.y * GX + blockIdx.x;
  id = (id & 7) * (NWG >> 3) + (id >> 3);
  const int m0 = (id / GX) * 128, n0 = (id % GX) * 128;
  const int wr = w >> 1, wc = w & 1;

  floatx4 acc[4][4];
#pragma unroll
  for (int m = 0; m < 4; ++m)
#pragma unroll
    for (int n = 0; n < 4; ++n) acc[m][n] = (floatx4){0.f, 0.f, 0.f, 0.f};

#define GSTAGE(BUF, T)                                                         \
  do {                                                                         \
    _Pragma("unroll") for (int p = 0; p < 4; ++p) {                            \
      const int c = p * 256 + tid;                                             \
      const int row = c >> 3;                                                  \
      const int co = ((c & 7) ^ (row & 7)) * 8;                                \
      GLL16(A + (size_t)(m0 + row) * K + (T) * 64 + co,                        \
            &As[BUF][(p * 256 + w * 64) * 8]);                                 \
      GLL16(B + (size_t)(n0 + row) * K + (T) * 64 + co,                        \
            &Bs[BUF][(p * 256 + w * 64) * 8]);                                 \
    }                                                                          \
  } while (0)

#define GCOMP(BUF)                                                             \
  do {                                                                         \
    _Pragma("unroll") for (int kk = 0; kk < 2; ++kk) {                         \
      short8 af[4], bfr[4];                                                    \
      _Pragma("unroll") for (int m = 0; m < 4; ++m)                            \
        af[m] = *reinterpret_cast<const short8*>(                              \
            &As[BUF][(wr * 64 + m * 16 + li) * 64 +                            \
                     (((kk * 4 + lg) ^ (li & 7)) * 8)]);                       \
      _Pragma("unroll") for (int n = 0; n < 4; ++n)                            \
        bfr[n] = *reinterpret_cast<const short8*>(                             \
            &Bs[BUF][(wc * 64 + n * 16 + li) * 64 +                            \
                     (((kk * 4 + lg) ^ (li & 7)) * 8)]);                       \
      __builtin_amdgcn_s_setprio(1);                                           \
      _Pragma("unroll") for (int m = 0; m < 4; ++m)                            \
        _Pragma("unroll") for (int n = 0; n < 4; ++n)                          \
            acc[m][n] = mfma16(af[m], bfr[n], acc[m][n]);                      \
      __builtin_amdgcn_s_setprio(0);                                           \
    }                                                                          \
  } while (0)

  const int NT = K >> 6;  // 16 for K=1024
  GSTAGE(0, 0);
  __syncthreads();
#pragma unroll 1
  for (int t = 0; t < NT; t += 2) {
    if (t + 1 < NT) GSTAGE(1, t + 1);
    GCOMP(0);
    __syncthreads();
    if (t + 2 < NT) GSTAGE(0, t + 2);
    GCOMP(1);
    __syncthreads();
  }
#undef GSTAGE
#undef GCOMP

#pragma unroll
  for (int m = 0; m < 4; ++m)
#pragma unroll
    for (int n = 0; n < 4; ++n) {
      const int gcol = n0 + wc * 64 + n * 16 + li;
      const float bv = bias[gcol];
      const int grow0 = m0 + wr * 64 + m * 16 + lg * 4;
      if (MODE == 1 && n0 >= 2048) {
        const int vc = gcol - 2048;
        const int hh = vc >> 6, dd = vc & 63;
        const int b = grow0 >> 11, s0 = grow0 & 2047;
        ushort4 pk;
        pk.x = f2b(acc[m][n][0] + bv);
        pk.y = f2b(acc[m][n][1] + bv);
        pk.z = f2b(acc[m][n][2] + bv);
        pk.w = f2b(acc[m][n][3] + bv);
        *reinterpret_cast<ushort4*>(
            &VT[((size_t)((b * NHEAD + hh) * HDIM + dd)) * SEQ + s0]) = pk;
      } else {
        const float scl =
            (MODE == 1 && gcol < 1024) ? 0.18033688011112042f : 1.f;
#pragma unroll
        for (int r = 0; r < 4; ++r) {
          const float val = (acc[m][n][r] + bv) * scl;
          if (MODE == 2)
            reinterpret_cast<float*>(C)[(size_t)(grow0 + r) * N + gcol] = val;
          else
            reinterpret_cast<unsigned short*>(C)[(size_t)(grow0 + r) * N + gcol] =
                f2b(val);
        }
      }
    }
}

// ---------------- Flash attention v7 (best: 95.6 us; frozen) ----------------
__global__ __launch_bounds__(512) void attn_v7(
    const unsigned short* __restrict__ QKV, const unsigned short* __restrict__ VT,
    const float* __restrict__ maskb, const unsigned int* __restrict__ flags2,
    unsigned short* __restrict__ O) {
  __shared__ __align__(16) unsigned short Kl[2][64 * 64];
  __shared__ __align__(16) unsigned short Vl[2][64 * 64];
  const int tid = threadIdx.x, w = tid >> 6, l = tid & 63;
  const int qi = l & 31, hi = l >> 5;
  const int bid = blockIdx.x;
  const int qblk = bid >> 6, bh = bid & 63, b = bh >> 4, h = bh & 15;
  const int q0 = qblk * 256 + w * 32;

  const unsigned short* qptr = QKV + (size_t)(b * SEQ + q0 + qi) * 3072 + h * 64;
  short8 qf[4];
#pragma unroll
  for (int ds = 0; ds < 4; ++ds)
    qf[ds] = *reinterpret_cast<const short8*>(qptr + ds * 16 + hi * 8);

  int off[2][4];
#pragma unroll
  for (int kb = 0; kb < 2; ++kb)
#pragma unroll
    for (int ds = 0; ds < 4; ++ds)
      off[kb][ds] = (kb * 32 + qi) * 64 + (((ds * 2 + hi) ^ (qi & 7)) * 8);

  const int srow = tid >> 3;
  const int swz = ((tid & 7) ^ (srow & 7)) * 8;
  const int ldst = w * 512;  // wave-uniform LDS base (ushort units)
  const unsigned short* kp0 =
      QKV + (size_t)(b * SEQ) * 3072 + D_MODEL + h * 64 + (size_t)srow * 3072 + swz;
  const unsigned short* vp0 =
      VT + (size_t)((b * NHEAD + h) * HDIM) * SEQ + (size_t)srow * SEQ + swz;

#define STAGE(BUF)                                                             \
  do {                                                                         \
    GLL16(kp0, &Kl[BUF][ldst]);                                                \
    GLL16(vp0, &Vl[BUF][ldst]);                                                \
    kp0 += 64 * 3072; vp0 += 64;                                               \
  } while (0)

  const float* mrow = maskb + b * SEQ;
  const unsigned int fl = flags2[b];
  f32x16 oa[2] = {};
  float l_run = 0.f;  // per-lane partial (own k-half); combined in epilogue

#define TILE(BUF, KT)                                                          \
  do {                                                                         \
    f32x16 pa0 = {}, pa1 = {};                                                 \
    __builtin_amdgcn_s_setprio(1);                                             \
    _Pragma("unroll") for (int ds = 0; ds < 4; ++ds) {                         \
      const short8 kf0 =                                                       \
          *reinterpret_cast<const short8*>(&Kl[BUF][off[0][ds]]);              \
      const short8 kf1 =                                                       \
          *reinterpret_cast<const short8*>(&Kl[BUF][off[1][ds]]);              \
      pa0 = mfma32(kf0, qf[ds], pa0);                                          \
      pa1 = mfma32(kf1, qf[ds], pa1);                                          \
    }                                                                          \
    __builtin_amdgcn_s_setprio(0);                                             \
    if (!((fl >> (KT)) & 1)) { /* slow path: some keys masked */               \
      _Pragma("unroll") for (int rq = 0; rq < 4; ++rq) {                       \
        const float4 m0 = *reinterpret_cast<const float4*>(                    \
            mrow + (KT) * 64 + rq * 8 + hi * 4);                               \
        const float4 m1 = *reinterpret_cast<const float4*>(                    \
            mrow + (KT) * 64 + 32 + rq * 8 + hi * 4);                          \
        pa0[rq * 4 + 0] += m0.x; pa0[rq * 4 + 1] += m0.y;                      \
        pa0[rq * 4 + 2] += m0.z; pa0[rq * 4 + 3] += m0.w;                      \
        pa1[rq * 4 + 0] += m1.x; pa1[rq * 4 + 1] += m1.y;                      \
        pa1[rq * 4 + 2] += m1.z; pa1[rq * 4 + 3] += m1.w;                      \
      }                                                                        \
    }                                                                          \
    float r0 = 0.f, r1 = 0.f, r2 = 0.f, r3 = 0.f;                              \
    _Pragma("unroll") for (int r = 0; r < 16; r += 4) {                        \
      float p;                                                                 \
      p = expfast(pa0[r + 0]); pa0[r + 0] = p; r0 += p;                        \
      p = expfast(pa0[r + 1]); pa0[r + 1] = p; r1 += p;                        \
      p = expfast(pa0[r + 2]); pa0[r + 2] = p; r2 += p;                        \
      p = expfast(pa0[r + 3]); pa0[r + 3] = p; r3 += p;                        \
      p = expfast(pa1[r + 0]); pa1[r + 0] = p; r0 += p;                        \
      p = expfast(pa1[r + 1]); pa1[r + 1] = p; r1 += p;                        \
      p = expfast(pa1[r + 2]); pa1[r + 2] = p; r2 += p;                        \
      p = expfast(pa1[r + 3]); pa1[r + 3] = p; r3 += p;                        \
    }                                                                          \
    l_run += (r0 + r1) + (r2 + r3);                                            \
    unsigned int c0[8], c1[8];                                                 \
    _Pragma("unroll") for (int u2 = 0; u2 < 8; ++u2) {                         \
      c0[u2] = cvtpk(pa0[2 * u2], pa0[2 * u2 + 1]);                            \
      c1[u2] = cvtpk(pa1[2 * u2], pa1[2 * u2 + 1]);                            \
    }                                                                          \
    pl32swap(c0[0], c0[2]); pl32swap(c0[1], c0[3]);                            \
    pl32swap(c0[4], c0[6]); pl32swap(c0[5], c0[7]);                            \
    pl32swap(c1[0], c1[2]); pl32swap(c1[1], c1[3]);                            \
    pl32swap(c1[4], c1[6]); pl32swap(c1[5], c1[7]);                            \
    __builtin_amdgcn_s_setprio(1);                                             \
    _Pragma("unroll") for (int ks = 0; ks < 4; ++ks) {                         \
      const int kb = ks >> 1, hf = (ks & 1) * 4;                               \
      const short8 pf = __builtin_bit_cast(                                    \
          short8, kb ? (uint4v){c1[hf], c1[hf + 1], c1[hf + 2], c1[hf + 3]}    \
                     : (uint4v){c0[hf], c0[hf + 1], c0[hf + 2], c0[hf + 3]});  \
      const short8 vf0 =                                                       \
          *reinterpret_cast<const short8*>(&Vl[BUF][off[0][ks]]);              \
      const short8 vf1 =                                                       \
          *reinterpret_cast<const short8*>(&Vl[BUF][off[1][ks]]);              \
      oa[0] = mfma32(vf0, pf, oa[0]);                                          \
      oa[1] = mfma32(vf1, pf, oa[1]);                                          \
    }                                                                          \
    __builtin_amdgcn_s_setprio(0);                                             \
  } while (0)

  STAGE(0);  // tile 0
  __syncthreads();
#pragma unroll 1
  for (int kt = 0; kt < 32; kt += 2) {
    STAGE(1);  // tile kt+1 in flight while computing kt
    TILE(0, kt);
    __syncthreads();
    if (kt + 2 < 32) STAGE(0);  // tile kt+2
    TILE(1, kt + 1);
    __syncthreads();
  }
#undef STAGE
#undef TILE

  // epilogue: combine lane-partial l across k-halves, normalize, repack, store
  l_run += __shfl_xor(l_run, 32);
  const float rinv = 1.f / l_run;
  unsigned int u[2][8];
#pragma unroll
  for (int vb = 0; vb < 2; ++vb) {
#pragma unroll
    for (int uu = 0; uu < 8; ++uu)
      u[vb][uu] = cvtpk(oa[vb][2 * uu] * rinv, oa[vb][2 * uu + 1] * rinv);
    pl32swap(u[vb][0], u[vb][2]);
    pl32swap(u[vb][1], u[vb][3]);
    pl32swap(u[vb][4], u[vb][6]);
    pl32swap(u[vb][5], u[vb][7]);
  }
  unsigned short* optr = O + (size_t)(b * SEQ + q0 + qi) * D_MODEL + h * 64;
#pragma unroll
  for (int cix = 0; cix < 4; ++cix) {
    const int vb = cix >> 1, hf = (cix & 1) * 4;
    *reinterpret_cast<short8*>(optr + cix * 16 + hi * 8) = __builtin_bit_cast(
        short8,
        (uint4v){u[vb][hf], u[vb][hf + 1], u[vb][hf + 2], u[vb][hf + 3]});
  }
}

// ---------------- launch ----------------
extern "C" void kernel_launch(void* const* d_in, const int* in_sizes, int n_in,
                              void* d_out, int out_size, void* d_ws, size_t ws_size,
                              hipStream_t stream) {
  const float* x  = (const float*)d_in[0];
  const int* mask = (const int*)d_in[1];
  const float* Wq = (const float*)d_in[2];
  const float* bq = (const float*)d_in[3];
  const float* Wk = (const float*)d_in[4];
  const float* bk = (const float*)d_in[5];
  const float* Wv = (const float*)d_in[6];
  const float* bv = (const float*)d_in[7];
  const float* Wo = (const float*)d_in[8];
  const float* bo = (const float*)d_in[9];

  char* ws = (char*)d_ws;
  const size_t SZ_X = (size_t)BATCH * SEQ * D_MODEL * 2;  // 16 MB
  unsigned short* xb    = (unsigned short*)(ws);                    // 16 MB @ 0
  unsigned short* Wqkvb = (unsigned short*)(ws + SZ_X);             // 6 MB @ 16M
  unsigned short* Wob   = (unsigned short*)(ws + SZ_X + 6u * 1024 * 1024);  // @ 22M
  unsigned short* QKVb  = (unsigned short*)(ws + 24u * 1024 * 1024);        // 48 MB
  unsigned short* VTb   = (unsigned short*)(ws + 72u * 1024 * 1024);        // 16 MB
  float*          bqkv  = (float*)(ws + 88u * 1024 * 1024);                 // 12 KB
  float*          maskb = (float*)(ws + 88u * 1024 * 1024 + 16384);         // 32 KB
  unsigned int*   flag2 = (unsigned int*)(ws + 88u * 1024 * 1024 + 49152);  // 16 B
  unsigned short* Ob    = xb;  // reuse: xb dead after QKV GEMM

  const int M = BATCH * SEQ;             // 8192

  prep<<<dim3(512, 6), 256, 0, stream>>>(x, xb, Wq, Wk, Wv, Wo, Wqkvb, Wob,
                                         mask, maskb, flag2, bq, bk, bv, bqkv);

  gemm_bt<1><<<dim3(3 * D_MODEL / 128, M / 128), 256, 0, stream>>>(
      xb, Wqkvb, bqkv, QKVb, VTb, M, 3 * D_MODEL, D_MODEL);

  attn_v7<<<BATCH * NHEAD * (SEQ / 256), 512, 0, stream>>>(QKVb, VTb, maskb,
                                                           flag2, Ob);

  gemm_bt<2><<<dim3(D_MODEL / 128, M / 128), 256, 0, stream>>>(
      Ob, Wob, bo, d_out, nullptr, M, D_MODEL, D_MODEL);
}